// Round 11
// baseline (1491.981 us; speedup 1.0000x reference)
//
#include <hip/hip_runtime.h>
#include <math.h>

// ---------------------------------------------------------------------------
// HDRNet, N=4, low 256x256, full 1024x1024. R17: 4-launch pipeline.
//   L1: conv0123_fused (R16 verbatim: LDS-staged low tile, 256 x 1024)
//   L2: mid_fused (NEW) — one kernel, two block families, no cross-block dep:
//       blocks 0..63 : l0+l1 tile-fused (4x4 l1 tile from 6x6 l0 tile
//                      recomputed from splat; 1.56x halo redundancy) -> localb
//       blocks 64..67: whole global branch per image in ONE block:
//                      a0 | g1->x1S(LDS 32KB) | a1 | g2->x2S(16KB) | a2 |
//                      FC 448->256->128->64 -> glob[n][64]
//       FP order per output replicates conv_p_dev's 16-partial split
//       (serial ascending sum), k5/k6's shfl-tree means, kfc's FC verbatim
//       -> bit-identical results.
//   L3: fuse_grid (384 x 256) — kfc minus FC: gl from glob, fuse -> grid
//   L4: hdr_out_v3 (74-77us, VALU-issue bound) (R7 verbatim)
// Evidence trail:
//   R7 352 (8L) | barriers parked (R8-R12) | R13 357 | R14 328.7 | R15 352
//   (T=1 regression) | R16 321.5 (LDS-staged conv0, -7us).
//   Budget model: fixed ~130us (matches ~39 harness reset dispatches/iter,
//   Dispatch_Id stride 44) + ~15us/launch + kernels ~116us.
// Predicted: 321.5 -> ~300-312 (one launch saved, k5+k6+kfc 13us -> ~9us).
// absmax 0.00390625 unchanged (bit-identical arithmetic everywhere).
// Workspace floats: t0 524288 (unused) | t1 262144 (unused) | t2 131072
// (unused) | splat 65536 | l0o 65536 (unused) | local 65536 | x1 32768
// (unused) | x2 16384 (unused) | avec 1792 (glob 256 floats live here) |
// grid 98304
// ---------------------------------------------------------------------------

__device__ __forceinline__ float tanh_fast(float x) {
    float e = __expf(2.0f * x);
    return 1.0f - 2.0f / (e + 1.0f);
}

// ======================= L1: fused conv0..conv3 (R16 verbatim) ==============
__global__ __launch_bounds__(1024) void conv0123_fused(
    const float* __restrict__ low,
    const float* __restrict__ w0, const float* __restrict__ b0,
    const float* __restrict__ w1, const float* __restrict__ b1,
    const float* __restrict__ w2, const float* __restrict__ b2,
    const float* __restrict__ w3, const float* __restrict__ b3,
    float* __restrict__ splat)
{
    __shared__ float lowT[3 * 47 * 47];
    __shared__ float t0s[8 * 529];
    __shared__ float t1s[16 * 121];
    __shared__ float t2s[32 * 25];
    const int tid = (int)threadIdx.x;
    const int n  = blockIdx.x >> 6;
    const int ty = (blockIdx.x >> 3) & 7;
    const int tx = blockIdx.x & 7;
    const int o0h = 16 * ty - 7, o0w = 16 * tx - 7;
    const int o1h = 8 * ty - 3,  o1w = 8 * tx - 3;
    const int o2h = 4 * ty - 1,  o2w = 4 * tx - 1;
    const int lh0 = 32 * ty - 15, lw0 = 32 * tx - 15;

    const float* lown = low + (size_t)n * 3 * 65536;
    for (int idx = tid; idx < 3 * 2209; idx += 1024) {
        int c = idx / 2209, p = idx - c * 2209;
        int r = p / 47, q = p - r * 47;
        int gh = lh0 + r, gw = lw0 + q;
        float v = 0.0f;
        if ((unsigned)gh < 256u && (unsigned)gw < 256u)
            v = lown[c * 65536 + gh * 256 + gw];
        lowT[idx] = v;
    }
    __syncthreads();

    for (int idx = tid; idx < 8 * 529; idx += 1024) {
        int c = idx / 529, p = idx - c * 529;
        int r = p / 23, q = p - r * 23;
        int h0 = o0h + r, w0g = o0w + q;
        float v = 0.0f;
        if ((unsigned)h0 < 128u && (unsigned)w0g < 128u) {
            float acc = b0[c];
            const float* wp = w0 + c * 27;
            #pragma unroll
            for (int ci = 0; ci < 3; ++ci) {
                const float* lc = lowT + ci * 2209;
                const float* wc = wp + ci * 9;
                #pragma unroll
                for (int kh = 0; kh < 3; ++kh) {
                    const float* rw = lc + (2 * r + kh) * 47 + 2 * q;
                    acc = fmaf(wc[kh * 3 + 0], rw[0], acc);
                    acc = fmaf(wc[kh * 3 + 1], rw[1], acc);
                    acc = fmaf(wc[kh * 3 + 2], rw[2], acc);
                }
            }
            v = fmaxf(acc, 0.0f);
        }
        t0s[idx] = v;
    }
    __syncthreads();

    for (int idx = tid; idx < 16 * 121; idx += 1024) {
        int c = idx / 121, p = idx - c * 121;
        int r = p / 11, q = p - r * 11;
        int h1 = o1h + r, w1g = o1w + q;
        float v = 0.0f;
        if ((unsigned)h1 < 64u && (unsigned)w1g < 64u) {
            float acc = b1[c];
            const float* wp = w1 + c * 72;
            #pragma unroll
            for (int ci = 0; ci < 8; ++ci) {
                const float* tc = t0s + ci * 529;
                const float* wc = wp + ci * 9;
                #pragma unroll
                for (int kh = 0; kh < 3; ++kh) {
                    const float* rw = tc + (2 * r + kh) * 23 + 2 * q;
                    acc = fmaf(wc[kh * 3 + 0], rw[0], acc);
                    acc = fmaf(wc[kh * 3 + 1], rw[1], acc);
                    acc = fmaf(wc[kh * 3 + 2], rw[2], acc);
                }
            }
            v = fmaxf(acc, 0.0f);
        }
        t1s[idx] = v;
    }
    __syncthreads();

    for (int idx = tid; idx < 32 * 25; idx += 1024) {
        int c = idx / 25, p = idx - c * 25;
        int r = p / 5, q = p - r * 5;
        int h2 = o2h + r, w2g = o2w + q;
        float v = 0.0f;
        if ((unsigned)h2 < 32u && (unsigned)w2g < 32u) {
            const float* wp = w2 + c * 144;
            float ps0 = 0, ps1 = 0, ps2 = 0, ps3 = 0;
            #pragma unroll
            for (int part = 0; part < 4; ++part) {
                float a = 0.0f;
                #pragma unroll
                for (int cc = 0; cc < 4; ++cc) {
                    int ci = part * 4 + cc;
                    const float* tc = t1s + ci * 121;
                    const float* wc = wp + ci * 9;
                    #pragma unroll
                    for (int kh = 0; kh < 3; ++kh) {
                        const float* rw = tc + (2 * r + kh) * 11 + 2 * q;
                        a = fmaf(wc[kh * 3 + 0], rw[0], a);
                        a = fmaf(wc[kh * 3 + 1], rw[1], a);
                        a = fmaf(wc[kh * 3 + 2], rw[2], a);
                    }
                }
                if (part == 0) ps0 = a; else if (part == 1) ps1 = a;
                else if (part == 2) ps2 = a; else ps3 = a;
            }
            float s = ps0; s += ps1; s += ps2; s += ps3;
            s += b2[c];
            v = fmaxf(s, 0.0f);
        }
        t2s[idx] = v;
    }
    __syncthreads();

    if (tid < 256) {
        int c = tid >> 2, sh = (tid >> 1) & 1, sw = tid & 1;
        int ho = 2 * ty + sh, wo = 2 * tx + sw;
        const float* wp = w3 + c * 288;
        float parts[8];
        #pragma unroll
        for (int part = 0; part < 8; ++part) {
            float a = 0.0f;
            #pragma unroll
            for (int cc = 0; cc < 4; ++cc) {
                int ci = part * 4 + cc;
                const float* tc = t2s + ci * 25;
                const float* wc = wp + ci * 9;
                #pragma unroll
                for (int kh = 0; kh < 3; ++kh) {
                    const float* rw = tc + (2 * sh + kh) * 5 + 2 * sw;
                    a = fmaf(wc[kh * 3 + 0], rw[0], a);
                    a = fmaf(wc[kh * 3 + 1], rw[1], a);
                    a = fmaf(wc[kh * 3 + 2], rw[2], a);
                }
            }
            parts[part] = a;
        }
        float s = parts[0];
        #pragma unroll
        for (int p = 1; p < 8; ++p) s += parts[p];
        s += b3[c];
        splat[(((size_t)(n * 64 + c)) * 16 + ho) * 16 + wo] = fmaxf(s, 0.0f);
    }
}

// ======================= L2: mid_fused ======================================
// blocks 0..63 : l0+l1 tile (n=bid>>4, 4x4 l1 tile at (4*t4y,4*t4x))
// blocks 64..67: global branch for image n=bid-64
__global__ __launch_bounds__(1024) void mid_fused(
    const float* __restrict__ splat,
    const float* __restrict__ wl0, const float* __restrict__ bl0,
    const float* __restrict__ wl1, float* __restrict__ localb,
    const float* __restrict__ wg1, const float* __restrict__ bg1,
    const float* __restrict__ wg2, const float* __restrict__ bg2,
    const float* __restrict__ wf1, const float* __restrict__ bf1,
    const float* __restrict__ wf2, const float* __restrict__ bf2,
    const float* __restrict__ wf3, const float* __restrict__ bf3,
    float* __restrict__ glob)
{
    __shared__ float l0T[64 * 36];    //  9 KB (l0l1 blocks)
    __shared__ float x1S[128 * 64];   // 32 KB (gchain blocks)
    __shared__ float x2S[256 * 16];   // 16 KB
    __shared__ float aS[448];
    __shared__ float h1S[256];
    __shared__ float h2S[128];
    const int tid = (int)threadIdx.x;
    const int bid = (int)blockIdx.x;

    if (bid < 64) {
        // ---------------- l0 + l1 tile-fused ----------------
        int n = bid >> 4, t4y = (bid >> 2) & 3, t4x = bid & 3;
        // stage A: l0 (relu, bias) on 6x6 tile at (4*t4y-1, 4*t4x-1).
        // conv_p_dev<64,16,1,true,true> order: 16 partials x 4 ci, asc sum.
        for (int idx = tid; idx < 64 * 36; idx += 1024) {
            int c = idx / 36, p = idx - c * 36;
            int r = p / 6, q = p - r * 6;
            int gh = 4 * t4y - 1 + r, gw = 4 * t4x - 1 + q;
            float v = 0.0f;
            if ((unsigned)gh < 16u && (unsigned)gw < 16u) {
                float s = 0.0f;
                const float* wp = wl0 + (size_t)c * 64 * 9;
                for (int pt = 0; pt < 16; ++pt) {
                    float a = 0.0f;
                    #pragma unroll
                    for (int cc = 0; cc < 4; ++cc) {
                        int ci = pt * 4 + cc;
                        const float* ip = splat + ((size_t)(n * 64 + ci)) * 256;
                        const float* wc = wp + ci * 9;
                        #pragma unroll
                        for (int kh = 0; kh < 3; ++kh) {
                            int hi = gh - 1 + kh;
                            if ((unsigned)hi >= 16u) continue;
                            const float* row = ip + hi * 16;
                            #pragma unroll
                            for (int kw = 0; kw < 3; ++kw) {
                                int wi = gw - 1 + kw;
                                if ((unsigned)wi >= 16u) continue;
                                a = fmaf(wc[kh * 3 + kw], row[wi], a);
                            }
                        }
                    }
                    if (pt == 0) s = a; else s += a;
                }
                s += bl0[c];
                v = fmaxf(s, 0.0f);
            }
            l0T[idx] = v;   // zero-filled OOB == original tap-skip semantics
        }
        __syncthreads();
        // stage B: l1 (no bias, no relu) 4x4 tile, 1 output/thread.
        {
            int c = tid >> 4, p = tid & 15;
            int r = p >> 2, q = p & 3;
            int oh = 4 * t4y + r, ow = 4 * t4x + q;
            float s = 0.0f;
            const float* wp = wl1 + (size_t)c * 64 * 9;
            for (int pt = 0; pt < 16; ++pt) {
                float a = 0.0f;
                #pragma unroll
                for (int cc = 0; cc < 4; ++cc) {
                    int ci = pt * 4 + cc;
                    const float* tc = l0T + ci * 36;
                    const float* wc = wp + ci * 9;
                    #pragma unroll
                    for (int kh = 0; kh < 3; ++kh) {
                        const float* rw = tc + (r + kh) * 6 + q;
                        a = fmaf(wc[kh * 3 + 0], rw[0], a);
                        a = fmaf(wc[kh * 3 + 1], rw[1], a);
                        a = fmaf(wc[kh * 3 + 2], rw[2], a);
                    }
                }
                if (pt == 0) s = a; else s += a;
            }
            localb[((size_t)(n * 64 + c)) * 256 + oh * 16 + ow] = s;
        }
    } else {
        // ---------------- global branch, one block per image ----------------
        int n = bid - 64;
        int wv = tid >> 6, lane = tid & 63;
        // phase 1: a0 means (k5 order: 4-term sum then shfl tree per wave)
        for (int it = 0; it < 4; ++it) {
            int c = wv + 16 * it;                       // 0..63
            const float* p = splat + ((size_t)(n * 64 + c)) * 256;
            float s = p[lane] + p[lane + 64] + p[lane + 128] + p[lane + 192];
            #pragma unroll
            for (int off = 32; off; off >>= 1) s += __shfl_down(s, off, 64);
            if (lane == 0) aS[c] = s * (1.0f / 256.0f);
        }
        // phase 2: g1 (relu,bias) -> x1S. conv_p_dev<64,16,2> order.
        for (int idx = tid; idx < 8192; idx += 1024) {
            int c = idx >> 6, p8 = idx & 63;
            int oh = p8 >> 3, ow = p8 & 7;
            int hi0 = oh * 2 - 1, wi0 = ow * 2 - 1;
            float s = 0.0f;
            const float* wp = wg1 + (size_t)c * 64 * 9;
            for (int pt = 0; pt < 16; ++pt) {
                float a = 0.0f;
                #pragma unroll
                for (int cc = 0; cc < 4; ++cc) {
                    int ci = pt * 4 + cc;
                    const float* ip = splat + ((size_t)(n * 64 + ci)) * 256;
                    const float* wc = wp + ci * 9;
                    #pragma unroll
                    for (int kh = 0; kh < 3; ++kh) {
                        int hi = hi0 + kh;
                        if ((unsigned)hi >= 16u) continue;
                        const float* row = ip + hi * 16;
                        #pragma unroll
                        for (int kw = 0; kw < 3; ++kw) {
                            int wi = wi0 + kw;
                            if ((unsigned)wi >= 16u) continue;
                            a = fmaf(wc[kh * 3 + kw], row[wi], a);
                        }
                    }
                }
                if (pt == 0) s = a; else s += a;
            }
            s += bg1[c];
            x1S[idx] = fmaxf(s, 0.0f);
        }
        __syncthreads();
        // phase 3: a1 means (k6 order: s=p[lane] then shfl tree)
        for (int it = 0; it < 8; ++it) {
            int c = wv + 16 * it;                       // 0..127
            float s = x1S[c * 64 + lane];
            #pragma unroll
            for (int off = 32; off; off >>= 1) s += __shfl_down(s, off, 64);
            if (lane == 0) aS[64 + c] = s * (1.0f / 64.0f);
        }
        // phase 4: g2 (relu,bias) -> x2S. conv_p_dev<128,16,2> order (8 ci).
        for (int idx = tid; idx < 4096; idx += 1024) {
            int c = idx >> 4, p4 = idx & 15;
            int oh = p4 >> 2, ow = p4 & 3;
            int hi0 = oh * 2 - 1, wi0 = ow * 2 - 1;
            float s = 0.0f;
            const float* wp = wg2 + (size_t)c * 128 * 9;
            for (int pt = 0; pt < 16; ++pt) {
                float a = 0.0f;
                #pragma unroll
                for (int cc = 0; cc < 8; ++cc) {
                    int ci = pt * 8 + cc;
                    const float* ip = x1S + ci * 64;
                    const float* wc = wp + ci * 9;
                    #pragma unroll
                    for (int kh = 0; kh < 3; ++kh) {
                        int hi = hi0 + kh;
                        if ((unsigned)hi >= 8u) continue;
                        const float* row = ip + hi * 8;
                        #pragma unroll
                        for (int kw = 0; kw < 3; ++kw) {
                            int wi = wi0 + kw;
                            if ((unsigned)wi >= 8u) continue;
                            a = fmaf(wc[kh * 3 + kw], row[wi], a);
                        }
                    }
                }
                if (pt == 0) s = a; else s += a;
            }
            s += bg2[c];
            x2S[idx] = fmaxf(s, 0.0f);
        }
        __syncthreads();
        // phase 5: a2 means (kfc order: serial 16-term sum)
        if (tid < 256) {
            const float* p = x2S + tid * 16;
            float s = 0.0f;
            #pragma unroll
            for (int i = 0; i < 16; ++i) s += p[i];
            aS[192 + tid] = s * (1.0f / 16.0f);
        }
        __syncthreads();
        // phase 6: FC chain (kfc verbatim against aS/h1S/h2S)
        if (tid < 256) {
            float a0 = 0, a1 = 0, a2 = 0, a3 = 0;
            const float* wp = wf1 + (size_t)tid * 448;
            for (int i = 0; i < 448; i += 4) {
                a0 = fmaf(wp[i], aS[i], a0); a1 = fmaf(wp[i + 1], aS[i + 1], a1);
                a2 = fmaf(wp[i + 2], aS[i + 2], a2); a3 = fmaf(wp[i + 3], aS[i + 3], a3);
            }
            h1S[tid] = fmaxf(a0 + a1 + a2 + a3 + bf1[tid], 0.0f);
        }
        __syncthreads();
        if (tid < 128) {
            float a0 = 0, a1 = 0, a2 = 0, a3 = 0;
            const float* wp = wf2 + (size_t)tid * 256;
            for (int i = 0; i < 256; i += 4) {
                a0 = fmaf(wp[i], h1S[i], a0); a1 = fmaf(wp[i + 1], h1S[i + 1], a1);
                a2 = fmaf(wp[i + 2], h1S[i + 2], a2); a3 = fmaf(wp[i + 3], h1S[i + 3], a3);
            }
            h2S[tid] = fmaxf(a0 + a1 + a2 + a3 + bf2[tid], 0.0f);
        }
        __syncthreads();
        if (tid < 64) {
            float a0 = 0, a1 = 0, a2 = 0, a3 = 0;
            const float* wp = wf3 + (size_t)tid * 128;
            for (int i = 0; i < 128; i += 4) {
                a0 = fmaf(wp[i], h2S[i], a0); a1 = fmaf(wp[i + 1], h2S[i + 1], a1);
                a2 = fmaf(wp[i + 2], h2S[i + 2], a2); a3 = fmaf(wp[i + 3], h2S[i + 3], a3);
            }
            glob[n * 64 + tid] = fmaxf(a0 + a1 + a2 + a3 + bf3[tid], 0.0f);
        }
    }
}

// ======================= L3: fuse_grid (kfc minus FC) =======================
__global__ __launch_bounds__(256) void fuse_grid_k(
    const float* __restrict__ glob, const float* __restrict__ localb,
    const float* __restrict__ wlin, const float* __restrict__ blin,
    float* __restrict__ grid)
{
    __shared__ float gl[64];
    int n = blockIdx.x / 96; int k = blockIdx.x % 96; int t = threadIdx.x;
    if (t < 64) gl[t] = glob[n * 64 + t];
    __syncthreads();
    float acc = blin[k];
    const float* wp = wlin + k * 64;
    const float* lo = localb + (size_t)n * 64 * 256 + t;
    #pragma unroll 8
    for (int c = 0; c < 64; ++c)
        acc = fmaf(wp[c], fmaxf(gl[c] + lo[c * 256], 0.0f), acc);
    grid[(size_t)n * 24576 + (size_t)t * 96 + (k & 7) * 12 + (k >> 3)] = acc;
}

// ======================= L4: hdr (R7 verbatim) ==============================
__global__ __launch_bounds__(256) void hdr_out_v3(
    const float* __restrict__ full, const float* __restrict__ low,
    const float* __restrict__ grid,
    const float* __restrict__ wgd1, const float* __restrict__ bgd1,
    const float* __restrict__ wgd2, const float* __restrict__ bgd2,
    const float* __restrict__ wau1, const float* __restrict__ bau1,
    const float* __restrict__ wau2, const float* __restrict__ bau2,
    const float* __restrict__ wav1, const float* __restrict__ bav1,
    const float* __restrict__ wav2, const float* __restrict__ bav2,
    float* __restrict__ out)
{
    int tid = blockIdx.x * 256 + threadIdx.x;
    int x = tid & 1023;
    int y = (tid >> 10) & 1023;
    int n = tid >> 20;
    const float* fp = full + ((size_t)n << 20);

    float v[3][3];
    #pragma unroll
    for (int r = 0; r < 3; ++r) {
        int yy = y + r - 1;
        bool okr = (unsigned)yy < 1024u;
        const float* row = fp + (size_t)yy * 1024;
        v[r][0] = (okr && x > 0)    ? row[x - 1] : 0.0f;
        v[r][1] = okr               ? row[x]     : 0.0f;
        v[r][2] = (okr && x < 1023) ? row[x + 1] : 0.0f;
    }

    float gacc = bgd2[0];
    #pragma unroll
    for (int k = 0; k < 16; ++k) {
        const float* wk = wgd1 + k * 9;
        float h = bgd1[k];
        h = fmaf(wk[0], v[0][0], h); h = fmaf(wk[1], v[0][1], h); h = fmaf(wk[2], v[0][2], h);
        h = fmaf(wk[3], v[1][0], h); h = fmaf(wk[4], v[1][1], h); h = fmaf(wk[5], v[1][2], h);
        h = fmaf(wk[6], v[2][0], h); h = fmaf(wk[7], v[2][1], h); h = fmaf(wk[8], v[2][2], h);
        gacc = fmaf(wgd2[k], fmaxf(h, 0.0f), gacc);
    }
    float g = tanh_fast(gacc);

    float gxc = (x * (32.0f / 1023.0f) - 1.0f) * 0.5f;
    float gyc = (y * (32.0f / 1023.0f) - 1.0f) * 0.5f;
    float gzc = 4.0f * g + 3.5f;
    float x0f = floorf(gxc), y0f = floorf(gyc), z0f = floorf(gzc);
    float fx = gxc - x0f, fy = gyc - y0f, fz = gzc - z0f;
    int ix = (int)x0f, iy = (int)y0f, iz = (int)z0f;

    float wx0 = (ix >= 0 && ix < 16) ? (1.0f - fx) : 0.0f;
    float wx1 = (ix + 1 < 16) ? fx : 0.0f;
    float wy0 = (iy >= 0 && iy < 16) ? (1.0f - fy) : 0.0f;
    float wy1 = (iy + 1 < 16) ? fy : 0.0f;
    float wz0 = (iz >= 0 && iz < 8) ? (1.0f - fz) : 0.0f;
    float wz1 = (iz + 1 >= 0 && iz + 1 < 8) ? fz : 0.0f;
    int xi0 = min(max(ix, 0), 15), xi1 = min(ix + 1, 15);
    int yi0 = min(max(iy, 0), 15), yi1 = min(iy + 1, 15);
    int zi0 = min(max(iz, 0), 7),  zi1 = min(max(iz + 1, 0), 7);

    float w00 = wy0 * wx0, w01 = wy0 * wx1, w10 = wy1 * wx0, w11 = wy1 * wx1;

    const float* gb = grid + (size_t)n * 24576;
    const float* c00 = gb + (yi0 * 16 + xi0) * 96;
    const float* c01 = gb + (yi0 * 16 + xi1) * 96;
    const float* c10 = gb + (yi1 * 16 + xi0) * 96;
    const float* c11 = gb + (yi1 * 16 + xi1) * 96;
    int zo0 = zi0 * 12;
    int zo1 = zi1 * 12;

    float acc[12];
    #pragma unroll
    for (int i = 0; i < 12; ++i) acc[i] = 0.0f;

    #define CORNER(PTR, WK) { \
        const float4* q = (const float4*)(PTR); \
        float wk_ = (WK); \
        float4 A = q[0], B = q[1], C = q[2]; \
        acc[0] = fmaf(wk_, A.x, acc[0]); acc[1] = fmaf(wk_, A.y, acc[1]); \
        acc[2] = fmaf(wk_, A.z, acc[2]); acc[3] = fmaf(wk_, A.w, acc[3]); \
        acc[4] = fmaf(wk_, B.x, acc[4]); acc[5] = fmaf(wk_, B.y, acc[5]); \
        acc[6] = fmaf(wk_, B.z, acc[6]); acc[7] = fmaf(wk_, B.w, acc[7]); \
        acc[8] = fmaf(wk_, C.x, acc[8]); acc[9] = fmaf(wk_, C.y, acc[9]); \
        acc[10] = fmaf(wk_, C.z, acc[10]); acc[11] = fmaf(wk_, C.w, acc[11]); }

    CORNER(c00 + zo0, wz0 * w00)
    CORNER(c01 + zo0, wz0 * w01)
    CORNER(c10 + zo0, wz0 * w10)
    CORNER(c11 + zo0, wz0 * w11)
    CORNER(c00 + zo1, wz1 * w00)
    CORNER(c01 + zo1, wz1 * w01)
    CORNER(c10 + zo1, wz1 * w10)
    CORNER(c11 + zo1, wz1 * w11)
    #undef CORNER

    float p = v[1][1];
    float Yv = fmaf(p, acc[3],  acc[0] + acc[1] + acc[2]);
    float U0 = fmaf(p, acc[7],  acc[4] + acc[5] + acc[6]);
    float V0 = fmaf(p, acc[11], acc[8] + acc[9] + acc[10]);

    float uacc = bau2[0];
    #pragma unroll
    for (int k = 0; k < 16; ++k)
        uacc = fmaf(wau2[k], fmaxf(fmaf(wau1[k], U0, bau1[k]), 0.0f), uacc);
    float vacc = bav2[0];
    #pragma unroll
    for (int k = 0; k < 16; ++k)
        vacc = fmaf(wav2[k], fmaxf(fmaf(wav1[k], V0, bav1[k]), 0.0f), vacc);

    float sx = (x + 0.5f) * 0.25f - 0.5f;
    float sy = (y + 0.5f) * 0.25f - 0.5f;
    float sxf = floorf(sx), syf = floorf(sy);
    float fxl = sx - sxf, fyl = sy - syf;
    int jx0 = max((int)sxf, 0), jx1 = min((int)sxf + 1, 255);
    int jy0 = max((int)syf, 0), jy1 = min((int)syf + 1, 255);
    const float* lr1 = low + ((size_t)(n * 3 + 1)) * 65536;
    const float* lr2 = low + ((size_t)(n * 3 + 2)) * 65536;
    float f1 = (1.0f - fyl) * ((1.0f - fxl) * lr1[jy0 * 256 + jx0] + fxl * lr1[jy0 * 256 + jx1])
             + fyl * ((1.0f - fxl) * lr1[jy1 * 256 + jx0] + fxl * lr1[jy1 * 256 + jx1]);
    float f2 = (1.0f - fyl) * ((1.0f - fxl) * lr2[jy0 * 256 + jx0] + fxl * lr2[jy0 * 256 + jx1])
             + fyl * ((1.0f - fxl) * lr2[jy1 * 256 + jx0] + fxl * lr2[jy1 * 256 + jx1]);

    float Uv = tanh_fast(uacc) + f1;
    float Vv = tanh_fast(vacc) + f2;

    size_t base = ((size_t)n * 3) * 1048576 + (size_t)y * 1024 + x;
    out[base]            = Yv;
    out[base + 1048576]  = Uv;
    out[base + 2097152]  = Vv;
}

extern "C" void kernel_launch(void* const* d_in, const int* in_sizes, int n_in,
                              void* d_out, int out_size, void* d_ws, size_t ws_size,
                              hipStream_t stream)
{
    const float* low  = (const float*)d_in[0];
    const float* full = (const float*)d_in[1];
    const float* w0 = (const float*)d_in[2];  const float* b0 = (const float*)d_in[3];
    const float* w1 = (const float*)d_in[4];  const float* b1 = (const float*)d_in[5];
    const float* w2 = (const float*)d_in[6];  const float* b2 = (const float*)d_in[7];
    const float* w3 = (const float*)d_in[8];  const float* b3 = (const float*)d_in[9];
    const float* wl0 = (const float*)d_in[10]; const float* bl0 = (const float*)d_in[11];
    const float* wl1 = (const float*)d_in[12];
    const float* wg1 = (const float*)d_in[13]; const float* bg1 = (const float*)d_in[14];
    const float* wg2 = (const float*)d_in[15]; const float* bg2 = (const float*)d_in[16];
    const float* wf1 = (const float*)d_in[17]; const float* bf1 = (const float*)d_in[18];
    const float* wf2 = (const float*)d_in[19]; const float* bf2 = (const float*)d_in[20];
    const float* wf3 = (const float*)d_in[21]; const float* bf3 = (const float*)d_in[22];
    const float* wlin = (const float*)d_in[23]; const float* blin = (const float*)d_in[24];
    const float* wgd1 = (const float*)d_in[25]; const float* bgd1 = (const float*)d_in[26];
    const float* wgd2 = (const float*)d_in[27]; const float* bgd2 = (const float*)d_in[28];
    const float* wau1 = (const float*)d_in[29]; const float* bau1 = (const float*)d_in[30];
    const float* wau2 = (const float*)d_in[31]; const float* bau2 = (const float*)d_in[32];
    const float* wav1 = (const float*)d_in[33]; const float* bav1 = (const float*)d_in[34];
    const float* wav2 = (const float*)d_in[35]; const float* bav2 = (const float*)d_in[36];
    float* out = (float*)d_out;

    float* ws = (float*)d_ws;
    float* t0b    = ws;                   // unused (kept for layout stability)
    float* t1b    = t0b + 524288;         // unused
    float* t2b    = t1b + 262144;         // unused
    float* splat  = t2b + 131072;
    float* l0o    = splat + 65536;        // unused (l0 now LDS-local)
    float* localb = l0o + 65536;
    float* x1b    = localb + 65536;       // unused (x1 now LDS-local)
    float* x2b    = x1b + 32768;          // unused (x2 now LDS-local)
    float* avec   = x2b + 16384;          // glob[256] lives here
    float* gridb  = avec + 1792;
    (void)t0b; (void)t1b; (void)l0o; (void)x1b; (void)x2b;
    float* glob = avec;

    conv0123_fused<<<256, 1024, 0, stream>>>(low, w0, b0, w1, b1, w2, b2, w3, b3, splat);
    mid_fused<<<68, 1024, 0, stream>>>(splat, wl0, bl0, wl1, localb,
                                       wg1, bg1, wg2, bg2,
                                       wf1, bf1, wf2, bf2, wf3, bf3, glob);
    fuse_grid_k<<<384, 256, 0, stream>>>(glob, localb, wlin, blin, gridb);
    hdr_out_v3<<<16384, 256, 0, stream>>>(full, low, gridb,
        wgd1, bgd1, wgd2, bgd2, wau1, bau1, wau2, bau2, wav1, bav1, wav2, bav2, out);
}

// Round 12
// 316.514 us; speedup vs baseline: 4.7138x; 4.7138x over previous
//
#include <hip/hip_runtime.h>
#include <math.h>

// ---------------------------------------------------------------------------
// HDRNet, N=4, low 256x256, full 1024x1024. R18: 5-launch pipeline.
//   = R16 (best verified, 321.5us) + ONE change: hdr interior fast-path.
//   L1: conv0123_fused (R16 verbatim: LDS-staged low tile, 256 x 1024)
//   L2: k5 {l0 || g1 || a0}   (R7 verbatim)
//   L3: k6 {l1 || g2 || a1}   (R7 verbatim)
//   L4: kfc (FC chain + grid fuse, z-innermost)  (R7 verbatim)
//   L5: hdr_out_v4 — R7's hdr + unconditional 3x3 window loads for interior
//       pixels (99.6%); boundary pixels keep checked path. Loaded values
//       identical -> bit-identical output.
// Evidence trail:
//   R7 352 | barriers parked (R8-R12: 50-135us/sync or hang) | R13 357 |
//   R14 328.7 | R15 352 (T=1 regression) | R16 321.5 (BEST) | R17 1492
//   (mid_fused: 68 blocks, VALUBusy 0.45% — serial-chain fusion killed
//   parallelism; 3rd occurrence of this mistake class).
// RULE (3x confirmed): never fuse into <~1000-block kernels with deep
// serial per-thread loops to save a ~15us launch — loses 10-100x more.
// Budget model: fixed ~130us + ~15us/launch + kernels ~112us (hdr 76,
// conv0123 ~28, k5 ~6, k6 ~5, kfc ~2).
// Predicted: 321.5 -> ~315-320 (hdr 76 -> 72-75). absmax 0.00390625.
// If hdr unchanged within noise: practical roofline at ~321, declare next.
// Workspace floats: t0 524288 (unused) | t1 262144 (unused) | t2 131072
// (unused) | splat 65536 | l0o 65536 | local 65536 | x1 32768 | x2 16384 |
// avec 1792 | grid 98304
// ---------------------------------------------------------------------------

__device__ __forceinline__ float tanh_fast(float x) {
    float e = __expf(2.0f * x);
    return 1.0f - 2.0f / (e + 1.0f);
}

// ======================= L1: fused conv0..conv3 (R16 verbatim) ==============
__global__ __launch_bounds__(1024) void conv0123_fused(
    const float* __restrict__ low,
    const float* __restrict__ w0, const float* __restrict__ b0,
    const float* __restrict__ w1, const float* __restrict__ b1,
    const float* __restrict__ w2, const float* __restrict__ b2,
    const float* __restrict__ w3, const float* __restrict__ b3,
    float* __restrict__ splat)
{
    __shared__ float lowT[3 * 47 * 47];
    __shared__ float t0s[8 * 529];
    __shared__ float t1s[16 * 121];
    __shared__ float t2s[32 * 25];
    const int tid = (int)threadIdx.x;
    const int n  = blockIdx.x >> 6;
    const int ty = (blockIdx.x >> 3) & 7;
    const int tx = blockIdx.x & 7;
    const int o0h = 16 * ty - 7, o0w = 16 * tx - 7;
    const int o1h = 8 * ty - 3,  o1w = 8 * tx - 3;
    const int o2h = 4 * ty - 1,  o2w = 4 * tx - 1;
    const int lh0 = 32 * ty - 15, lw0 = 32 * tx - 15;

    const float* lown = low + (size_t)n * 3 * 65536;
    for (int idx = tid; idx < 3 * 2209; idx += 1024) {
        int c = idx / 2209, p = idx - c * 2209;
        int r = p / 47, q = p - r * 47;
        int gh = lh0 + r, gw = lw0 + q;
        float v = 0.0f;
        if ((unsigned)gh < 256u && (unsigned)gw < 256u)
            v = lown[c * 65536 + gh * 256 + gw];
        lowT[idx] = v;
    }
    __syncthreads();

    for (int idx = tid; idx < 8 * 529; idx += 1024) {
        int c = idx / 529, p = idx - c * 529;
        int r = p / 23, q = p - r * 23;
        int h0 = o0h + r, w0g = o0w + q;
        float v = 0.0f;
        if ((unsigned)h0 < 128u && (unsigned)w0g < 128u) {
            float acc = b0[c];
            const float* wp = w0 + c * 27;
            #pragma unroll
            for (int ci = 0; ci < 3; ++ci) {
                const float* lc = lowT + ci * 2209;
                const float* wc = wp + ci * 9;
                #pragma unroll
                for (int kh = 0; kh < 3; ++kh) {
                    const float* rw = lc + (2 * r + kh) * 47 + 2 * q;
                    acc = fmaf(wc[kh * 3 + 0], rw[0], acc);
                    acc = fmaf(wc[kh * 3 + 1], rw[1], acc);
                    acc = fmaf(wc[kh * 3 + 2], rw[2], acc);
                }
            }
            v = fmaxf(acc, 0.0f);
        }
        t0s[idx] = v;
    }
    __syncthreads();

    for (int idx = tid; idx < 16 * 121; idx += 1024) {
        int c = idx / 121, p = idx - c * 121;
        int r = p / 11, q = p - r * 11;
        int h1 = o1h + r, w1g = o1w + q;
        float v = 0.0f;
        if ((unsigned)h1 < 64u && (unsigned)w1g < 64u) {
            float acc = b1[c];
            const float* wp = w1 + c * 72;
            #pragma unroll
            for (int ci = 0; ci < 8; ++ci) {
                const float* tc = t0s + ci * 529;
                const float* wc = wp + ci * 9;
                #pragma unroll
                for (int kh = 0; kh < 3; ++kh) {
                    const float* rw = tc + (2 * r + kh) * 23 + 2 * q;
                    acc = fmaf(wc[kh * 3 + 0], rw[0], acc);
                    acc = fmaf(wc[kh * 3 + 1], rw[1], acc);
                    acc = fmaf(wc[kh * 3 + 2], rw[2], acc);
                }
            }
            v = fmaxf(acc, 0.0f);
        }
        t1s[idx] = v;
    }
    __syncthreads();

    for (int idx = tid; idx < 32 * 25; idx += 1024) {
        int c = idx / 25, p = idx - c * 25;
        int r = p / 5, q = p - r * 5;
        int h2 = o2h + r, w2g = o2w + q;
        float v = 0.0f;
        if ((unsigned)h2 < 32u && (unsigned)w2g < 32u) {
            const float* wp = w2 + c * 144;
            float ps0 = 0, ps1 = 0, ps2 = 0, ps3 = 0;
            #pragma unroll
            for (int part = 0; part < 4; ++part) {
                float a = 0.0f;
                #pragma unroll
                for (int cc = 0; cc < 4; ++cc) {
                    int ci = part * 4 + cc;
                    const float* tc = t1s + ci * 121;
                    const float* wc = wp + ci * 9;
                    #pragma unroll
                    for (int kh = 0; kh < 3; ++kh) {
                        const float* rw = tc + (2 * r + kh) * 11 + 2 * q;
                        a = fmaf(wc[kh * 3 + 0], rw[0], a);
                        a = fmaf(wc[kh * 3 + 1], rw[1], a);
                        a = fmaf(wc[kh * 3 + 2], rw[2], a);
                    }
                }
                if (part == 0) ps0 = a; else if (part == 1) ps1 = a;
                else if (part == 2) ps2 = a; else ps3 = a;
            }
            float s = ps0; s += ps1; s += ps2; s += ps3;
            s += b2[c];
            v = fmaxf(s, 0.0f);
        }
        t2s[idx] = v;
    }
    __syncthreads();

    if (tid < 256) {
        int c = tid >> 2, sh = (tid >> 1) & 1, sw = tid & 1;
        int ho = 2 * ty + sh, wo = 2 * tx + sw;
        const float* wp = w3 + c * 288;
        float parts[8];
        #pragma unroll
        for (int part = 0; part < 8; ++part) {
            float a = 0.0f;
            #pragma unroll
            for (int cc = 0; cc < 4; ++cc) {
                int ci = part * 4 + cc;
                const float* tc = t2s + ci * 25;
                const float* wc = wp + ci * 9;
                #pragma unroll
                for (int kh = 0; kh < 3; ++kh) {
                    const float* rw = tc + (2 * sh + kh) * 5 + 2 * sw;
                    a = fmaf(wc[kh * 3 + 0], rw[0], a);
                    a = fmaf(wc[kh * 3 + 1], rw[1], a);
                    a = fmaf(wc[kh * 3 + 2], rw[2], a);
                }
            }
            parts[part] = a;
        }
        float s = parts[0];
        #pragma unroll
        for (int p = 1; p < 8; ++p) s += parts[p];
        s += b3[c];
        splat[(((size_t)(n * 64 + c)) * 16 + ho) * 16 + wo] = fmaxf(s, 0.0f);
    }
}

// ---- PARTS-way input-channel-split 3x3 conv (R7 verbatim) ----
template<int CIN, int PARTS, int STRIDE, bool RELU, bool HASB,
         int COUT, int HIN, int WIN, int HOUT, int WOUT>
__device__ __forceinline__ void conv_p_dev(
    const float* __restrict__ in, const float* __restrict__ w,
    const float* __restrict__ b, float* __restrict__ out,
    int tb, float* red)
{
    constexpr int CPT = CIN / PARTS;
    constexpr int OPB = 256 / PARTS;
    int part = threadIdx.x / OPB;
    int oidx = threadIdx.x % OPB;
    int o = tb * OPB + oidx;
    int wo = o % WOUT; int t = o / WOUT;
    int ho = t % HOUT; t /= HOUT;
    int co = t % COUT; int n = t / COUT;
    int hi0 = ho * STRIDE - 1, wi0 = wo * STRIDE - 1;
    const float* wp = w + ((size_t)co * CIN + part * CPT) * 9;
    const float* ip = in + ((size_t)n * CIN + part * CPT) * HIN * WIN;
    float acc = 0.0f;
    #pragma unroll
    for (int ci = 0; ci < CPT; ++ci) {
        const float* ic = ip + (size_t)ci * HIN * WIN;
        const float* wc = wp + ci * 9;
        #pragma unroll
        for (int kh = 0; kh < 3; ++kh) {
            int hi = hi0 + kh;
            if ((unsigned)hi >= (unsigned)HIN) continue;
            const float* row = ic + hi * WIN;
            #pragma unroll
            for (int kw = 0; kw < 3; ++kw) {
                int wi = wi0 + kw;
                if ((unsigned)wi >= (unsigned)WIN) continue;
                acc = fmaf(wc[kh * 3 + kw], row[wi], acc);
            }
        }
    }
    red[threadIdx.x] = acc;
    __syncthreads();
    if (part == 0) {
        float s = acc;
        #pragma unroll
        for (int p = 1; p < PARTS; ++p) s += red[p * OPB + oidx];
        if (HASB) s += b[co];
        if (RELU) s = fmaxf(s, 0.0f);
        out[o] = s;
    }
}

// ======================= L2: k5 {l0 || g1 || a0} (R7 verbatim) ==============
__global__ __launch_bounds__(256) void k5_l0_g1_means(
    const float* __restrict__ splat,
    const float* __restrict__ wl0, const float* __restrict__ bl0, float* __restrict__ l0o,
    const float* __restrict__ wg1, const float* __restrict__ bg1, float* __restrict__ x1,
    float* __restrict__ avec)
{
    __shared__ float red[256];
    int bid = blockIdx.x;
    if (bid < 4096) {
        conv_p_dev<64, 16, 1, true, true, 64, 16, 16, 16, 16>(splat, wl0, bl0, l0o, bid, red);
    } else if (bid < 6144) {
        conv_p_dev<64, 16, 2, true, true, 128, 16, 16, 8, 8>(splat, wg1, bg1, x1, bid - 4096, red);
    } else {
        int wid = (bid - 6144) * 4 + ((int)threadIdx.x >> 6);   // 0..255
        int lane = threadIdx.x & 63;
        int n = wid >> 6, c = wid & 63;
        const float* p = splat + ((size_t)(n * 64 + c)) * 256;
        float s = p[lane] + p[lane + 64] + p[lane + 128] + p[lane + 192];
        #pragma unroll
        for (int off = 32; off; off >>= 1) s += __shfl_down(s, off, 64);
        if (lane == 0) avec[n * 448 + c] = s * (1.0f / 256.0f);
    }
}

// ======================= L3: k6 {l1 || g2 || a1} (R7 verbatim) ==============
__global__ __launch_bounds__(256) void k6_l1_g2_means(
    const float* __restrict__ l0o, const float* __restrict__ wl1, float* __restrict__ localb,
    const float* __restrict__ x1, const float* __restrict__ wg2,
    const float* __restrict__ bg2, float* __restrict__ x2,
    float* __restrict__ avec)
{
    __shared__ float red[256];
    int bid = blockIdx.x;
    if (bid < 4096) {
        conv_p_dev<64, 16, 1, false, false, 64, 16, 16, 16, 16>(l0o, wl1, nullptr, localb, bid, red);
    } else if (bid < 5120) {
        conv_p_dev<128, 16, 2, true, true, 256, 8, 8, 4, 4>(x1, wg2, bg2, x2, bid - 4096, red);
    } else {
        int wid = (bid - 5120) * 4 + ((int)threadIdx.x >> 6);   // 0..511
        int lane = threadIdx.x & 63;
        int n = wid >> 7, c = wid & 127;
        const float* p = x1 + ((size_t)(n * 128 + c)) * 64;
        float s = p[lane];
        #pragma unroll
        for (int off = 32; off; off >>= 1) s += __shfl_down(s, off, 64);
        if (lane == 0) avec[n * 448 + 64 + c] = s * (1.0f / 64.0f);
    }
}

// ======================= L4: kfc (R7 verbatim, z-innermost grid) ============
__global__ __launch_bounds__(256) void kfc_fuse(
    const float* __restrict__ avec, const float* __restrict__ x2,
    const float* __restrict__ wf1, const float* __restrict__ bf1,
    const float* __restrict__ wf2, const float* __restrict__ bf2,
    const float* __restrict__ wf3, const float* __restrict__ bf3,
    const float* __restrict__ local,
    const float* __restrict__ wlin, const float* __restrict__ blin,
    float* __restrict__ grid)
{
    __shared__ float a[448];
    __shared__ float h1[256];
    __shared__ float h2[128];
    __shared__ float gl[64];
    int n = blockIdx.x / 96; int k = blockIdx.x % 96; int t = threadIdx.x;
    if (t < 192) a[t] = avec[n * 448 + t];
    {
        const float* p = x2 + ((size_t)(n * 256 + t)) * 16;
        float s = 0.0f;
        #pragma unroll
        for (int i = 0; i < 16; ++i) s += p[i];
        a[192 + t] = s * (1.0f / 16.0f);
    }
    __syncthreads();
    {
        float a0 = 0, a1 = 0, a2 = 0, a3 = 0;
        const float* wp = wf1 + (size_t)t * 448;
        for (int i = 0; i < 448; i += 4) {
            a0 = fmaf(wp[i], a[i], a0); a1 = fmaf(wp[i + 1], a[i + 1], a1);
            a2 = fmaf(wp[i + 2], a[i + 2], a2); a3 = fmaf(wp[i + 3], a[i + 3], a3);
        }
        h1[t] = fmaxf(a0 + a1 + a2 + a3 + bf1[t], 0.0f);
    }
    __syncthreads();
    if (t < 128) {
        float a0 = 0, a1 = 0, a2 = 0, a3 = 0;
        const float* wp = wf2 + (size_t)t * 256;
        for (int i = 0; i < 256; i += 4) {
            a0 = fmaf(wp[i], h1[i], a0); a1 = fmaf(wp[i + 1], h1[i + 1], a1);
            a2 = fmaf(wp[i + 2], h1[i + 2], a2); a3 = fmaf(wp[i + 3], h1[i + 3], a3);
        }
        h2[t] = fmaxf(a0 + a1 + a2 + a3 + bf2[t], 0.0f);
    }
    __syncthreads();
    if (t < 64) {
        float a0 = 0, a1 = 0, a2 = 0, a3 = 0;
        const float* wp = wf3 + (size_t)t * 128;
        for (int i = 0; i < 128; i += 4) {
            a0 = fmaf(wp[i], h2[i], a0); a1 = fmaf(wp[i + 1], h2[i + 1], a1);
            a2 = fmaf(wp[i + 2], h2[i + 2], a2); a3 = fmaf(wp[i + 3], h2[i + 3], a3);
        }
        gl[t] = fmaxf(a0 + a1 + a2 + a3 + bf3[t], 0.0f);
    }
    __syncthreads();
    float acc = blin[k];
    const float* wp = wlin + k * 64;
    const float* lo = local + (size_t)n * 64 * 256 + t;
    #pragma unroll 8
    for (int c = 0; c < 64; ++c)
        acc = fmaf(wp[c], fmaxf(gl[c] + lo[c * 256], 0.0f), acc);
    grid[(size_t)n * 24576 + (size_t)t * 96 + (k & 7) * 12 + (k >> 3)] = acc;
}

// ======================= L5: hdr v4 (interior fast-path window) =============
__global__ __launch_bounds__(256) void hdr_out_v4(
    const float* __restrict__ full, const float* __restrict__ low,
    const float* __restrict__ grid,
    const float* __restrict__ wgd1, const float* __restrict__ bgd1,
    const float* __restrict__ wgd2, const float* __restrict__ bgd2,
    const float* __restrict__ wau1, const float* __restrict__ bau1,
    const float* __restrict__ wau2, const float* __restrict__ bau2,
    const float* __restrict__ wav1, const float* __restrict__ bav1,
    const float* __restrict__ wav2, const float* __restrict__ bav2,
    float* __restrict__ out)
{
    int tid = blockIdx.x * 256 + threadIdx.x;
    int x = tid & 1023;
    int y = (tid >> 10) & 1023;
    int n = tid >> 20;
    const float* fp = full + ((size_t)n << 20);

    // 3x3 window: unconditional loads for interior pixels (99.6%),
    // checked path for boundary. Values identical -> bit-identical output.
    float v[3][3];
    if ((unsigned)(x - 1) < 1022u && (unsigned)(y - 1) < 1022u) {
        const float* rm = fp + (size_t)(y - 1) * 1024 + x;
        const float* r0 = fp + (size_t)y * 1024 + x;
        const float* rp = fp + (size_t)(y + 1) * 1024 + x;
        v[0][0] = rm[-1]; v[0][1] = rm[0]; v[0][2] = rm[1];
        v[1][0] = r0[-1]; v[1][1] = r0[0]; v[1][2] = r0[1];
        v[2][0] = rp[-1]; v[2][1] = rp[0]; v[2][2] = rp[1];
    } else {
        #pragma unroll
        for (int r = 0; r < 3; ++r) {
            int yy = y + r - 1;
            bool okr = (unsigned)yy < 1024u;
            const float* row = fp + (size_t)yy * 1024;
            v[r][0] = (okr && x > 0)    ? row[x - 1] : 0.0f;
            v[r][1] = okr               ? row[x]     : 0.0f;
            v[r][2] = (okr && x < 1023) ? row[x + 1] : 0.0f;
        }
    }

    float gacc = bgd2[0];
    #pragma unroll
    for (int k = 0; k < 16; ++k) {
        const float* wk = wgd1 + k * 9;
        float h = bgd1[k];
        h = fmaf(wk[0], v[0][0], h); h = fmaf(wk[1], v[0][1], h); h = fmaf(wk[2], v[0][2], h);
        h = fmaf(wk[3], v[1][0], h); h = fmaf(wk[4], v[1][1], h); h = fmaf(wk[5], v[1][2], h);
        h = fmaf(wk[6], v[2][0], h); h = fmaf(wk[7], v[2][1], h); h = fmaf(wk[8], v[2][2], h);
        gacc = fmaf(wgd2[k], fmaxf(h, 0.0f), gacc);
    }
    float g = tanh_fast(gacc);

    float gxc = (x * (32.0f / 1023.0f) - 1.0f) * 0.5f;
    float gyc = (y * (32.0f / 1023.0f) - 1.0f) * 0.5f;
    float gzc = 4.0f * g + 3.5f;
    float x0f = floorf(gxc), y0f = floorf(gyc), z0f = floorf(gzc);
    float fx = gxc - x0f, fy = gyc - y0f, fz = gzc - z0f;
    int ix = (int)x0f, iy = (int)y0f, iz = (int)z0f;

    float wx0 = (ix >= 0 && ix < 16) ? (1.0f - fx) : 0.0f;
    float wx1 = (ix + 1 < 16) ? fx : 0.0f;
    float wy0 = (iy >= 0 && iy < 16) ? (1.0f - fy) : 0.0f;
    float wy1 = (iy + 1 < 16) ? fy : 0.0f;
    float wz0 = (iz >= 0 && iz < 8) ? (1.0f - fz) : 0.0f;
    float wz1 = (iz + 1 >= 0 && iz + 1 < 8) ? fz : 0.0f;
    int xi0 = min(max(ix, 0), 15), xi1 = min(ix + 1, 15);
    int yi0 = min(max(iy, 0), 15), yi1 = min(iy + 1, 15);
    int zi0 = min(max(iz, 0), 7),  zi1 = min(max(iz + 1, 0), 7);

    float w00 = wy0 * wx0, w01 = wy0 * wx1, w10 = wy1 * wx0, w11 = wy1 * wx1;

    const float* gb = grid + (size_t)n * 24576;
    const float* c00 = gb + (yi0 * 16 + xi0) * 96;
    const float* c01 = gb + (yi0 * 16 + xi1) * 96;
    const float* c10 = gb + (yi1 * 16 + xi0) * 96;
    const float* c11 = gb + (yi1 * 16 + xi1) * 96;
    int zo0 = zi0 * 12;
    int zo1 = zi1 * 12;

    float acc[12];
    #pragma unroll
    for (int i = 0; i < 12; ++i) acc[i] = 0.0f;

    #define CORNER(PTR, WK) { \
        const float4* q = (const float4*)(PTR); \
        float wk_ = (WK); \
        float4 A = q[0], B = q[1], C = q[2]; \
        acc[0] = fmaf(wk_, A.x, acc[0]); acc[1] = fmaf(wk_, A.y, acc[1]); \
        acc[2] = fmaf(wk_, A.z, acc[2]); acc[3] = fmaf(wk_, A.w, acc[3]); \
        acc[4] = fmaf(wk_, B.x, acc[4]); acc[5] = fmaf(wk_, B.y, acc[5]); \
        acc[6] = fmaf(wk_, B.z, acc[6]); acc[7] = fmaf(wk_, B.w, acc[7]); \
        acc[8] = fmaf(wk_, C.x, acc[8]); acc[9] = fmaf(wk_, C.y, acc[9]); \
        acc[10] = fmaf(wk_, C.z, acc[10]); acc[11] = fmaf(wk_, C.w, acc[11]); }

    CORNER(c00 + zo0, wz0 * w00)
    CORNER(c01 + zo0, wz0 * w01)
    CORNER(c10 + zo0, wz0 * w10)
    CORNER(c11 + zo0, wz0 * w11)
    CORNER(c00 + zo1, wz1 * w00)
    CORNER(c01 + zo1, wz1 * w01)
    CORNER(c10 + zo1, wz1 * w10)
    CORNER(c11 + zo1, wz1 * w11)
    #undef CORNER

    float p = v[1][1];
    float Yv = fmaf(p, acc[3],  acc[0] + acc[1] + acc[2]);
    float U0 = fmaf(p, acc[7],  acc[4] + acc[5] + acc[6]);
    float V0 = fmaf(p, acc[11], acc[8] + acc[9] + acc[10]);

    float uacc = bau2[0];
    #pragma unroll
    for (int k = 0; k < 16; ++k)
        uacc = fmaf(wau2[k], fmaxf(fmaf(wau1[k], U0, bau1[k]), 0.0f), uacc);
    float vacc = bav2[0];
    #pragma unroll
    for (int k = 0; k < 16; ++k)
        vacc = fmaf(wav2[k], fmaxf(fmaf(wav1[k], V0, bav1[k]), 0.0f), vacc);

    float sx = (x + 0.5f) * 0.25f - 0.5f;
    float sy = (y + 0.5f) * 0.25f - 0.5f;
    float sxf = floorf(sx), syf = floorf(sy);
    float fxl = sx - sxf, fyl = sy - syf;
    int jx0 = max((int)sxf, 0), jx1 = min((int)sxf + 1, 255);
    int jy0 = max((int)syf, 0), jy1 = min((int)syf + 1, 255);
    const float* lr1 = low + ((size_t)(n * 3 + 1)) * 65536;
    const float* lr2 = low + ((size_t)(n * 3 + 2)) * 65536;
    float f1 = (1.0f - fyl) * ((1.0f - fxl) * lr1[jy0 * 256 + jx0] + fxl * lr1[jy0 * 256 + jx1])
             + fyl * ((1.0f - fxl) * lr1[jy1 * 256 + jx0] + fxl * lr1[jy1 * 256 + jx1]);
    float f2 = (1.0f - fyl) * ((1.0f - fxl) * lr2[jy0 * 256 + jx0] + fxl * lr2[jy0 * 256 + jx1])
             + fyl * ((1.0f - fxl) * lr2[jy1 * 256 + jx0] + fxl * lr2[jy1 * 256 + jx1]);

    float Uv = tanh_fast(uacc) + f1;
    float Vv = tanh_fast(vacc) + f2;

    size_t base = ((size_t)n * 3) * 1048576 + (size_t)y * 1024 + x;
    out[base]            = Yv;
    out[base + 1048576]  = Uv;
    out[base + 2097152]  = Vv;
}

extern "C" void kernel_launch(void* const* d_in, const int* in_sizes, int n_in,
                              void* d_out, int out_size, void* d_ws, size_t ws_size,
                              hipStream_t stream)
{
    const float* low  = (const float*)d_in[0];
    const float* full = (const float*)d_in[1];
    const float* w0 = (const float*)d_in[2];  const float* b0 = (const float*)d_in[3];
    const float* w1 = (const float*)d_in[4];  const float* b1 = (const float*)d_in[5];
    const float* w2 = (const float*)d_in[6];  const float* b2 = (const float*)d_in[7];
    const float* w3 = (const float*)d_in[8];  const float* b3 = (const float*)d_in[9];
    const float* wl0 = (const float*)d_in[10]; const float* bl0 = (const float*)d_in[11];
    const float* wl1 = (const float*)d_in[12];
    const float* wg1 = (const float*)d_in[13]; const float* bg1 = (const float*)d_in[14];
    const float* wg2 = (const float*)d_in[15]; const float* bg2 = (const float*)d_in[16];
    const float* wf1 = (const float*)d_in[17]; const float* bf1 = (const float*)d_in[18];
    const float* wf2 = (const float*)d_in[19]; const float* bf2 = (const float*)d_in[20];
    const float* wf3 = (const float*)d_in[21]; const float* bf3 = (const float*)d_in[22];
    const float* wlin = (const float*)d_in[23]; const float* blin = (const float*)d_in[24];
    const float* wgd1 = (const float*)d_in[25]; const float* bgd1 = (const float*)d_in[26];
    const float* wgd2 = (const float*)d_in[27]; const float* bgd2 = (const float*)d_in[28];
    const float* wau1 = (const float*)d_in[29]; const float* bau1 = (const float*)d_in[30];
    const float* wau2 = (const float*)d_in[31]; const float* bau2 = (const float*)d_in[32];
    const float* wav1 = (const float*)d_in[33]; const float* bav1 = (const float*)d_in[34];
    const float* wav2 = (const float*)d_in[35]; const float* bav2 = (const float*)d_in[36];
    float* out = (float*)d_out;

    float* ws = (float*)d_ws;
    float* t0b    = ws;                   // unused (kept for layout stability)
    float* t1b    = t0b + 524288;         // unused
    float* t2b    = t1b + 262144;         // unused
    float* splat  = t2b + 131072;
    float* l0o    = splat + 65536;
    float* localb = l0o + 65536;
    float* x1b    = localb + 65536;
    float* x2b    = x1b + 32768;
    float* avec   = x2b + 16384;
    float* gridb  = avec + 1792;
    (void)t0b; (void)t1b;

    conv0123_fused<<<256, 1024, 0, stream>>>(low, w0, b0, w1, b1, w2, b2, w3, b3, splat);
    k5_l0_g1_means<<<6208, 256, 0, stream>>>(splat, wl0, bl0, l0o, wg1, bg1, x1b, avec);
    k6_l1_g2_means<<<5248, 256, 0, stream>>>(l0o, wl1, localb, x1b, wg2, bg2, x2b, avec);
    kfc_fuse<<<384, 256, 0, stream>>>(avec, x2b, wf1, bf1, wf2, bf2, wf3, bf3,
                                      localb, wlin, blin, gridb);
    hdr_out_v4<<<16384, 256, 0, stream>>>(full, low, gridb,
        wgd1, bgd1, wgd2, bgd2, wau1, bau1, wau2, bau2, wav1, bav1, wav2, bav2, out);
}